// Round 2
// baseline (19285.710 us; speedup 1.0000x reference)
//
#include <hip/hip_runtime.h>
#include <stdint.h>

#define SEQ 512
#define BATCH 128
#define INDIM 256
#define HID 256
#define CS 512

typedef _Float16 f16;
typedef __attribute__((ext_vector_type(8))) _Float16 f16x8;
typedef __attribute__((ext_vector_type(4))) _Float16 f16x4;
typedef __attribute__((ext_vector_type(4))) float f32x4;

// ws layout:
//   [0,1MB)        wx   : [2][1024 n][256 k] f16   (Wx in B^T row-major)
//   [1MB,1MB+8KB)  bias : [2048] f32
//   [2MB,4MB)      ex   : [2 dir][8 bt][4 slot][16 row][256 hid] u32 tagged-h
//   [4MB,...)      gx   : [nd][4096 mt][1024 n][16 mw] f16  (128MB per dir)
#define WX_OFF   0u
#define BIAS_OFF (1u<<20)
#define EX_OFF   (2u<<20)
#define GX_OFF   (4u<<20)

__device__ __forceinline__ float sigm(float x) { return 1.0f / (1.0f + __expf(-x)); }
__device__ __forceinline__ float tanh_fast(float x) { return 1.0f - 2.0f / (__expf(2.0f * x) + 1.0f); }

__device__ __forceinline__ void load_lds16(const void* g, void* l) {
  __builtin_amdgcn_global_load_lds((const __attribute__((address_space(1))) void*)g,
                                   (__attribute__((address_space(3))) void*)l, 16, 0, 0);
}

// ---------------- kernel 1: convert Wx -> f16, build bias table ----------------
struct PrepP { const float* W[8]; const float* Bv[8]; f16* wx; float* bias; };

__global__ __launch_bounds__(256) void k_prep(PrepP p) {
  const int u = blockIdx.x * 256 + threadIdx.x;       // 131072 threads exactly
  const int k4 = (u & 63) * 4;
  const int n = (u >> 6) & 1023;
  const int dir = u >> 16;
  const float* src = p.W[dir * 4 + (n >> 8)] + (size_t)(n & 255) * CS + INDIM + k4;
  f32x4 a = *(const f32x4*)src;
  f16x4 v;
  #pragma unroll
  for (int j = 0; j < 4; ++j) v[j] = (f16)a[j];
  *(f16x4*)(p.wx + ((size_t)dir * 1024 + n) * 256 + k4) = v;
  if (u < 2048) p.bias[u] = p.Bv[(u >> 10) * 4 + ((u >> 8) & 3)][u & 255];
}

// ---------------- kernel 2: Gx = X @ Wx^T + b  (f16 out, permuted layout) ------
struct GemP { const float* X; const f16* wx; const float* bias; f16* gx; int d0, nd; };

__global__ __launch_bounds__(256) void k_gemm(GemP p) {
  __shared__ float As[128 * 64];   // 32KB, rows 256B, XOR-swizzled
  __shared__ f16   Bs[128 * 64];   // 16KB, rows 128B, XOR-swizzled
  const int tid = threadIdx.x, l = tid & 63, w = tid >> 6;
  const int lp = l & 15, lg = l >> 4;
  const int NB = 8 * p.nd;
  const int nb = blockIdx.x % NB, mb = blockIdx.x / NB;
  const int n_g0 = p.d0 * 1024 + nb * 128;
  const int m0 = mb * 128;
  const int wm = w >> 1, wn = w & 1;

  f32x4 acc[4][4];
  #pragma unroll
  for (int a = 0; a < 4; ++a) {
    #pragma unroll
    for (int b = 0; b < 4; ++b) acc[a][b] = (f32x4){0.f, 0.f, 0.f, 0.f};
  }

  auto stage = [&](int kb) {
    #pragma unroll
    for (int j = 0; j < 8; ++j) {            // A: 32 x 1KB insts total
      const int i = w * 8 + j;
      const int rl = i * 4 + lg;             // local row 0..127
      const int kc = (lp * 16) ^ ((rl & 7) << 4);
      const char* g = (const char*)p.X + ((size_t)(m0 + rl) * 256 + (size_t)kb * 64) * 4 + kc;
      load_lds16(g, (char*)As + i * 1024 + l * 16);
    }
    #pragma unroll
    for (int j = 0; j < 4; ++j) {            // B: 16 x 1KB insts total
      const int i = w * 4 + j;
      const int rl = i * 8 + (l >> 3);
      const int kc = ((l & 7) * 16) ^ ((rl & 7) << 4);
      const char* g = (const char*)p.wx + ((size_t)(n_g0 + rl) * 256 + (size_t)kb * 64) * 2 + kc;
      load_lds16(g, (char*)Bs + i * 1024 + l * 16);
    }
  };

  stage(0);
  for (int kb = 0; kb < 4; ++kb) {
    __syncthreads();                          // drains vmcnt -> tiles ready
    #pragma unroll
    for (int ks = 0; ks < 2; ++ks) {
      f16x8 af[4];
      #pragma unroll
      for (int mi = 0; mi < 4; ++mi) {
        const int r = wm * 64 + mi * 16 + lp;
        const int kbyte = ks * 128 + lg * 32;
        const int sw = (r & 7) << 4;
        f32x4 a0 = *(const f32x4*)((const char*)As + r * 256 + (kbyte ^ sw));
        f32x4 a1 = *(const f32x4*)((const char*)As + r * 256 + ((kbyte + 16) ^ sw));
        f16x8 v;
        #pragma unroll
        for (int j = 0; j < 4; ++j) { v[j] = (f16)a0[j]; v[4 + j] = (f16)a1[j]; }
        af[mi] = v;
      }
      #pragma unroll
      for (int ni = 0; ni < 4; ++ni) {
        const int rn = wn * 64 + ni * 16 + lp;
        const int kbyte = (ks * 64 + lg * 16) ^ ((rn & 7) << 4);
        f16x8 bf = *(const f16x8*)((const char*)Bs + rn * 128 + kbyte);
        #pragma unroll
        for (int mi = 0; mi < 4; ++mi)
          acc[mi][ni] = __builtin_amdgcn_mfma_f32_16x16x32_f16(af[mi], bf, acc[mi][ni], 0, 0, 0);
      }
    }
    if (kb < 3) { __syncthreads(); stage(kb + 1); }
  }

  // epilogue: +bias, f16, permuted store [gd][mt][nn][mw]
  #pragma unroll
  for (int ni = 0; ni < 4; ++ni) {
    const int n_g = n_g0 + wn * 64 + ni * 16 + lp;
    const float bv = p.bias[n_g];
    const int gdl = (n_g >> 10) - p.d0;
    const int nn = n_g & 1023;
    #pragma unroll
    for (int mi = 0; mi < 4; ++mi) {
      const int mt = (m0 + wm * 64 + mi * 16) >> 4;
      f16x4 h4;
      #pragma unroll
      for (int r = 0; r < 4; ++r) h4[r] = (f16)(acc[mi][ni][r] + bv);
      *(f16x4*)((char*)p.gx + (((size_t)gdl * 4096 + mt) * 1024 + nn) * 32 + lg * 8) = h4;
    }
  }
}

// ---------------- kernel 3: barrier-free tagged recurrence ---------------------
struct RecP { const float* W[8]; const f16* gx; uint32_t* ex; float* out; int d0; };

__global__ __launch_bounds__(256, 1) void k_rec(RecP p) {
  const int tid = threadIdx.x;
  const int l = tid & 63;
  const int lp = l & 15, lg = l >> 4;
  const int bx = blockIdx.x;
  const int gd = bx >> 4;                 // gx dir index within this pass
  const int dir = p.d0 + gd;
  const int bt = (bx >> 1) & 7;
  const int gw = (bx & 1) * 4 + (tid >> 6);   // logical wave 0..7 in group
  const int hid0 = gw * 32;

  // Wh B-fragments in registers: 4 gates x 2 hid-tiles x 8 k-steps
  f16x8 Bf[4][2][8];
  #pragma unroll
  for (int g = 0; g < 4; ++g) {
    #pragma unroll
    for (int hh = 0; hh < 2; ++hh) {
      const float* wb = p.W[dir * 4 + g] + (size_t)(hid0 + hh * 16 + lp) * CS;
      #pragma unroll
      for (int ks = 0; ks < 8; ++ks) {
        const float* s = wb + ks * 32 + lg * 8;
        f32x4 a = *(const f32x4*)s;
        f32x4 b = *(const f32x4*)(s + 4);
        f16x8 v;
        #pragma unroll
        for (int j = 0; j < 4; ++j) { v[j] = (f16)a[j]; v[4 + j] = (f16)b[j]; }
        Bf[g][hh][ks] = v;
      }
    }
  }

  uint32_t* exg = p.ex + (size_t)(dir * 8 + bt) * (4 * 16 * 256);
  const char* gxb = (const char*)p.gx + (size_t)gd * 4096 * 1024 * 32;

  float c[2][4];
  #pragma unroll
  for (int hh = 0; hh < 2; ++hh) {
    #pragma unroll
    for (int r = 0; r < 4; ++r) c[hh][r] = 0.f;
  }

  int tt = dir ? (SEQ - 1) : 0;
  const int stp = dir ? -1 : 1;

  f16x4 gxv[4][2];
  {
    const char* gb = gxb + (size_t)(tt * 8 + bt) * 1024 * 32 + lg * 8;
    #pragma unroll
    for (int g = 0; g < 4; ++g) {
      #pragma unroll
      for (int hh = 0; hh < 2; ++hh)
        gxv[g][hh] = *(const f16x4*)(gb + (size_t)(g * 256 + hid0 + hh * 16 + lp) * 32);
    }
  }

  uint32_t sv[64];   // speculative tagged-h words for next step (static indices)

  for (int t = 0; t < SEQ; ++t, tt += stp) {
    f32x4 acc[4][2];
    #pragma unroll
    for (int g = 0; g < 4; ++g) {
      #pragma unroll
      for (int hh = 0; hh < 2; ++hh) acc[g][hh] = (f32x4){0.f, 0.f, 0.f, 0.f};
    }

    if (t > 0) {
      const uint32_t txor = (uint32_t)(t - 1) << 16;
      uint32_t mx = 0;
      #pragma unroll
      for (int i = 0; i < 64; ++i) { uint32_t x = sv[i] ^ txor; mx = x > mx ? x : mx; }
      while (__ballot(mx < 0x10000u) != 0xFFFFFFFFFFFFFFFFull) {
        __builtin_amdgcn_s_sleep(2);
        const uint32_t* eb = exg + ((t - 1) & 3) * 4096 + lp * 256 + lg * 8;
        #pragma unroll
        for (int ks = 0; ks < 8; ++ks) {
          #pragma unroll
          for (int j = 0; j < 8; ++j)
            sv[ks * 8 + j] = __hip_atomic_load(eb + ks * 32 + j, __ATOMIC_RELAXED, __HIP_MEMORY_SCOPE_AGENT);
        }
        mx = 0;
        #pragma unroll
        for (int i = 0; i < 64; ++i) { uint32_t x = sv[i] ^ txor; mx = x > mx ? x : mx; }
      }
      #pragma unroll
      for (int ks = 0; ks < 8; ++ks) {
        f16x8 a;
        #pragma unroll
        for (int j = 0; j < 8; ++j) {
          union { uint16_t u; f16 f; } cv;
          cv.u = (uint16_t)(sv[ks * 8 + j] & 0xffffu);
          a[j] = cv.f;
        }
        #pragma unroll
        for (int g = 0; g < 4; ++g) {
          acc[g][0] = __builtin_amdgcn_mfma_f32_16x16x32_f16(a, Bf[g][0][ks], acc[g][0], 0, 0, 0);
          acc[g][1] = __builtin_amdgcn_mfma_f32_16x16x32_f16(a, Bf[g][1][ks], acc[g][1], 0, 0, 0);
        }
      }
    }

    // gates -> c,h ; publish tagged h ; write out (f32)
    #pragma unroll
    for (int hh = 0; hh < 2; ++hh) {
      const int hid = hid0 + hh * 16 + lp;
      #pragma unroll
      for (int r = 0; r < 4; ++r) {
        float pf = acc[0][hh][r] + (float)gxv[0][hh][r];
        float pi = acc[1][hh][r] + (float)gxv[1][hh][r];
        float pc = acc[2][hh][r] + (float)gxv[2][hh][r];
        float po = acc[3][hh][r] + (float)gxv[3][hh][r];
        float fg = sigm(pf), ig = sigm(pi), cg = tanh_fast(pc), og = sigm(po);
        float cn = fg * c[hh][r] + ig * cg;
        c[hh][r] = cn;
        float h = og * tanh_fast(cn);
        const int row = lg * 4 + r;
        union { f16 f; uint16_t u; } hb; hb.f = (f16)h;
        __hip_atomic_store(exg + (t & 3) * 4096 + row * 256 + hid,
                           ((uint32_t)t << 16) | (uint32_t)hb.u,
                           __ATOMIC_RELAXED, __HIP_MEMORY_SCOPE_AGENT);
        p.out[((size_t)tt * 128 + bt * 16 + row) * 512 + dir * 256 + hid] = h;
      }
    }

    // prefetch gx for next step (clamped at the ends; wasted loads are harmless)
    {
      int ttn = tt + stp;
      ttn = ttn < 0 ? 0 : (ttn > SEQ - 1 ? SEQ - 1 : ttn);
      const char* gb = gxb + (size_t)(ttn * 8 + bt) * 1024 * 32 + lg * 8;
      #pragma unroll
      for (int g = 0; g < 4; ++g) {
        #pragma unroll
        for (int hh = 0; hh < 2; ++hh)
          gxv[g][hh] = *(const f16x4*)(gb + (size_t)(g * 256 + hid0 + hh * 16 + lp) * 32);
      }
    }
    // speculative loads of h(t) for next step
    {
      const uint32_t* eb = exg + (t & 3) * 4096 + lp * 256 + lg * 8;
      #pragma unroll
      for (int ks = 0; ks < 8; ++ks) {
        #pragma unroll
        for (int j = 0; j < 8; ++j)
          sv[ks * 8 + j] = __hip_atomic_load(eb + ks * 32 + j, __ATOMIC_RELAXED, __HIP_MEMORY_SCOPE_AGENT);
      }
    }
  }
}

// ---------------- launch -------------------------------------------------------
extern "C" void kernel_launch(void* const* d_in, const int* in_sizes, int n_in,
                              void* d_out, int out_size, void* d_ws, size_t ws_size,
                              hipStream_t stream) {
  (void)in_sizes; (void)n_in; (void)out_size;
  PrepP pp;
  const float* X = (const float*)d_in[0];
  for (int i = 0; i < 8; ++i) {
    pp.W[i]  = (const float*)d_in[1 + 2 * i];
    pp.Bv[i] = (const float*)d_in[2 + 2 * i];
  }
  char* ws = (char*)d_ws;
  pp.wx = (f16*)(ws + WX_OFF);
  pp.bias = (float*)(ws + BIAS_OFF);
  uint32_t* ex = (uint32_t*)(ws + EX_OFF);
  f16* gx = (f16*)(ws + GX_OFF);

  const size_t per_dir = (size_t)4096 * 1024 * 32;   // 128MB
  int nd;
  if (ws_size >= (size_t)GX_OFF + 2 * per_dir) nd = 2;
  else if (ws_size >= (size_t)GX_OFF + per_dir) nd = 1;
  else return;  // insufficient workspace

  k_prep<<<dim3(512), dim3(256), 0, stream>>>(pp);

  const int passes = (nd == 2) ? 1 : 2;
  for (int ps = 0; ps < passes; ++ps) {
    const int d0 = (nd == 2) ? 0 : ps;
    GemP gp; gp.X = X; gp.wx = pp.wx; gp.bias = pp.bias; gp.gx = gx; gp.d0 = d0; gp.nd = nd;
    k_gemm<<<dim3(512 * 8 * nd), dim3(256), 0, stream>>>(gp);
    RecP rp;
    for (int i = 0; i < 8; ++i) rp.W[i] = pp.W[i];
    rp.gx = gx; rp.ex = ex; rp.out = (float*)d_out; rp.d0 = d0;
    k_rec<<<dim3(16 * nd), dim3(256), 0, stream>>>(rp);
  }
}

// Round 3
// 3270.266 us; speedup vs baseline: 5.8973x; 5.8973x over previous
//
#include <hip/hip_runtime.h>
#include <stdint.h>

#define SEQ 512
#define BATCH 128
#define INDIM 256
#define HID 256
#define CS 512

typedef _Float16 f16;
typedef __attribute__((ext_vector_type(8))) _Float16 f16x8;
typedef __attribute__((ext_vector_type(4))) _Float16 f16x4;
typedef __attribute__((ext_vector_type(4))) float f32x4;

// ws layout:
//   [0,1MB)        wx   : [2][1024 n][256 k] f16
//   [1MB,1MB+8KB)  bias : [2048] f32
//   [4MB,...)      gx   : per dir 128MB: [mt 4096][w 4][g*2+cp 8][lane 64][16B]
#define WX_OFF   0u
#define BIAS_OFF (1u<<20)
#define GX_OFF   (4u<<20)
#define GXD ((size_t)4096 * 32768)   // 128MB per dir

__device__ __forceinline__ float sigm(float x) { return 1.0f / (1.0f + __expf(-x)); }
__device__ __forceinline__ float tanh_fast(float x) { return 1.0f - 2.0f / (__expf(2.0f * x) + 1.0f); }

__device__ __forceinline__ void load_lds16(const void* g, void* l) {
  __builtin_amdgcn_global_load_lds((const __attribute__((address_space(1))) void*)g,
                                   (__attribute__((address_space(3))) void*)l, 16, 0, 0);
}

// ---------------- kernel 1: Wx -> f16, bias table ------------------------------
struct PrepP { const float* W[8]; const float* Bv[8]; f16* wx; float* bias; };

__global__ __launch_bounds__(256) void k_prep(PrepP p) {
  const int u = blockIdx.x * 256 + threadIdx.x;       // 131072 threads exactly
  const int k4 = (u & 63) * 4;
  const int n = (u >> 6) & 1023;
  const int dir = u >> 16;
  const float* src = p.W[dir * 4 + (n >> 8)] + (size_t)(n & 255) * CS + HID + k4;
  f32x4 a = *(const f32x4*)src;
  f16x4 v;
  #pragma unroll
  for (int j = 0; j < 4; ++j) v[j] = (f16)a[j];
  *(f16x4*)(p.wx + ((size_t)dir * 1024 + n) * 256 + k4) = v;
  if (u < 2048) p.bias[u] = p.Bv[(u >> 10) * 4 + ((u >> 8) & 3)][u & 255];
}

// ---------------- kernel 2: Gx = X @ Wx^T + b  (f16, k_rec-DMA layout) ----------
struct GemP { const float* X; const f16* wx; const float* bias; f16* gx; int d0, nd; };

__global__ __launch_bounds__(256) void k_gemm(GemP p) {
  __shared__ float As[128 * 64];   // 32KB, rows 256B, XOR-swizzled
  __shared__ f16   Bs[128 * 64];   // 16KB, rows 128B, XOR-swizzled
  const int tid = threadIdx.x, l = tid & 63, w = tid >> 6;
  const int lp = l & 15, lg = l >> 4;
  const int NB = 8 * p.nd;
  const int nb = blockIdx.x % NB, mb = blockIdx.x / NB;
  const int m0 = mb * 128;
  const int wm = w >> 1, wn = w & 1;

  f32x4 acc[4][4];
  #pragma unroll
  for (int a = 0; a < 4; ++a)
    #pragma unroll
    for (int b = 0; b < 4; ++b) acc[a][b] = (f32x4){0.f, 0.f, 0.f, 0.f};

  auto stage = [&](int kb) {
    #pragma unroll
    for (int j = 0; j < 8; ++j) {
      const int i = w * 8 + j;
      const int rl = i * 4 + lg;
      const int kc = (lp * 16) ^ ((rl & 7) << 4);
      const char* g = (const char*)p.X + ((size_t)(m0 + rl) * 256 + (size_t)kb * 64) * 4 + kc;
      load_lds16(g, (char*)As + i * 1024 + l * 16);
    }
    #pragma unroll
    for (int j = 0; j < 4; ++j) {
      const int i = w * 4 + j;
      const int rl = i * 8 + (l >> 3);
      const int kc = ((l & 7) * 16) ^ ((rl & 7) << 4);
      const char* g = (const char*)p.wx + ((size_t)(p.d0 * 1024 + nb * 128 + rl) * 256 + (size_t)kb * 64) * 2 + kc;
      load_lds16(g, (char*)Bs + i * 1024 + l * 16);
    }
  };

  stage(0);
  for (int kb = 0; kb < 4; ++kb) {
    __syncthreads();
    #pragma unroll
    for (int ks = 0; ks < 2; ++ks) {
      f16x8 af[4];
      #pragma unroll
      for (int mi = 0; mi < 4; ++mi) {
        const int r = wm * 64 + mi * 16 + lp;
        const int kbyte = ks * 128 + lg * 32;
        const int sw = (r & 7) << 4;
        f32x4 a0 = *(const f32x4*)((const char*)As + r * 256 + (kbyte ^ sw));
        f32x4 a1 = *(const f32x4*)((const char*)As + r * 256 + ((kbyte + 16) ^ sw));
        f16x8 v;
        #pragma unroll
        for (int j = 0; j < 4; ++j) { v[j] = (f16)a0[j]; v[4 + j] = (f16)a1[j]; }
        af[mi] = v;
      }
      #pragma unroll
      for (int ni = 0; ni < 4; ++ni) {
        const int rn = wn * 64 + ni * 16 + lp;
        const int kbyte = (ks * 64 + lg * 16) ^ ((rn & 7) << 4);
        f16x8 bf = *(const f16x8*)((const char*)Bs + rn * 128 + kbyte);
        #pragma unroll
        for (int mi = 0; mi < 4; ++mi)
          acc[mi][ni] = __builtin_amdgcn_mfma_f32_16x16x32_f16(af[mi], bf, acc[mi][ni], 0, 0, 0);
      }
    }
    if (kb < 3) { __syncthreads(); stage(kb + 1); }
  }

  // epilogue: +bias, f16, store in k_rec DMA layout
  #pragma unroll
  for (int ni = 0; ni < 4; ++ni) {
    const int n_all = nb * 128 + wn * 64 + ni * 16 + lp;
    const float bv = p.bias[p.d0 * 1024 + n_all];
    const int gdl = n_all >> 10;
    const int n = n_all & 1023;
    const int g = n >> 8, hid = n & 255;
    const int wr = hid >> 6, c = (hid >> 4) & 3;
    #pragma unroll
    for (int mi = 0; mi < 4; ++mi) {
      const int mt = (m0 + wm * 64 + mi * 16) >> 4;
      f16x4 h4;
      #pragma unroll
      for (int r = 0; r < 4; ++r) h4[r] = (f16)(acc[mi][ni][r] + bv);
      char* dst = (char*)p.gx + (size_t)gdl * GXD
                + ((((size_t)mt * 4 + wr) * 8) + g * 2 + (c >> 1)) * 1024
                + (size_t)l * 16 + (c & 1) * 8;
      *(f16x4*)dst = h4;
    }
  }
}

// ---------------- kernel 3: block-local recurrence (no global sync) ------------
// LDS: [0,114688)   wt: wave w at w*28672, fid=(g*4+c)*2+(ks-6), ct 0..13
//      [114688,122880) h: 16 rows x 256 hid f16, byte ^= (row&7)<<4
//      [122880,155648) gx: wave w at +w*8192, 8 chunks x 64 lanes x 16B
#define HB_OFF 114688
#define GXB_OFF 122880
#define REC_LDS 155648

struct RecP { const float* W[8]; const f16* gx; float* out; int d0; };

__global__ __launch_bounds__(256, 1) void k_rec(RecP p) {
  extern __shared__ char smem[];
  const int tid = threadIdx.x, l = tid & 63, w = tid >> 6;
  const int lp = l & 15, lg = l >> 4;
  const int bx = blockIdx.x;
  const int dirl = bx >> 3;
  const int dir = p.d0 + dirl;
  const int bt = bx & 7;

  char* wtb = smem + w * 28672;
  char* gxb = smem + GXB_OFF + w * 8192;
  const char* gxd = (const char*)p.gx + (size_t)dirl * GXD;

  // ---- weights: f32 -> f16 fragments; ks<6 in regs, ks 6..7 in LDS (ct<14) ----
  f16x8 Br[4][4][6];
  f16x8 Brx[2][2];   // ct 14,15 = (g=3,c=2),(g=3,c=3), ks 6..7
  #pragma unroll
  for (int g = 0; g < 4; ++g) {
    #pragma unroll
    for (int c = 0; c < 4; ++c) {
      const float* wr = p.W[dir * 4 + g] + (size_t)(w * 64 + c * 16 + lp) * CS;
      #pragma unroll
      for (int ks = 0; ks < 8; ++ks) {
        f32x4 a0 = *(const f32x4*)(wr + ks * 32 + lg * 8);
        f32x4 a1 = *(const f32x4*)(wr + ks * 32 + lg * 8 + 4);
        f16x8 v;
        #pragma unroll
        for (int j = 0; j < 4; ++j) { v[j] = (f16)a0[j]; v[4 + j] = (f16)a1[j]; }
        if (ks < 6) Br[g][c][ks] = v;
        else if (g == 3 && c >= 2) Brx[c - 2][ks - 6] = v;
        else *(f16x8*)(wtb + ((g * 4 + c) * 2 + (ks - 6)) * 1024 + (size_t)l * 16) = v;
      }
    }
  }

  float cst[4][4];
  #pragma unroll
  for (int c = 0; c < 4; ++c)
    #pragma unroll
    for (int r = 0; r < 4; ++r) cst[c][r] = 0.f;

  int tt = dir ? (SEQ - 1) : 0;
  const int stp = dir ? -1 : 1;

  auto issue_gx = [&](int mt) {
    const char* src = gxd + (((size_t)mt * 4 + w) * 8) * 1024 + (size_t)l * 16;
    #pragma unroll
    for (int ch = 0; ch < 8; ++ch)
      load_lds16(src + ch * 1024, gxb + ch * 1024 + (size_t)l * 16);
  };

  issue_gx(tt * 8 + bt);

  for (int t = 0; t < SEQ; ++t, tt += stp) {
    f16x8 a[8];
    if (t > 0) {
      #pragma unroll
      for (int ks = 0; ks < 8; ++ks) {
        const int byte = (lp * 512 + ks * 64 + lg * 16) ^ ((lp & 7) << 4);
        a[ks] = *(const f16x8*)(smem + HB_OFF + byte);
      }
    }
    // barrier1: h reads done (lgkm) -> safe for everyone to overwrite h
    asm volatile("s_waitcnt lgkmcnt(0)" ::: "memory");
    __builtin_amdgcn_sched_barrier(0);
    __builtin_amdgcn_s_barrier();
    // gx DMA for this step landed (wave-private)
    asm volatile("s_waitcnt vmcnt(0)" ::: "memory");
    __builtin_amdgcn_sched_barrier(0);

    #pragma unroll
    for (int c = 0; c < 4; ++c) {
      f32x4 acc[4];
      #pragma unroll
      for (int g = 0; g < 4; ++g) {
        f16x4 gv = *(const f16x4*)(gxb + (g * 2 + (c >> 1)) * 1024 + (size_t)l * 16 + (c & 1) * 8);
        #pragma unroll
        for (int r = 0; r < 4; ++r) acc[g][r] = (float)gv[r];
      }
      if (t > 0) {
        #pragma unroll
        for (int ks = 0; ks < 6; ++ks)
          #pragma unroll
          for (int g = 0; g < 4; ++g)
            acc[g] = __builtin_amdgcn_mfma_f32_16x16x32_f16(a[ks], Br[g][c][ks], acc[g], 0, 0, 0);
        #pragma unroll
        for (int k2 = 0; k2 < 2; ++k2)
          #pragma unroll
          for (int g = 0; g < 4; ++g) {
            f16x8 bv;
            if (g == 3 && c >= 2) bv = Brx[c - 2][k2];
            else bv = *(const f16x8*)(wtb + ((g * 4 + c) * 2 + k2) * 1024 + (size_t)l * 16);
            acc[g] = __builtin_amdgcn_mfma_f32_16x16x32_f16(a[6 + k2], bv, acc[g], 0, 0, 0);
          }
      }
      #pragma unroll
      for (int r = 0; r < 4; ++r) {
        const float fg = sigm(acc[0][r]);
        const float ig = sigm(acc[1][r]);
        const float cg = tanh_fast(acc[2][r]);
        const float og = sigm(acc[3][r]);
        const float cn = fg * cst[c][r] + ig * cg;
        cst[c][r] = cn;
        const float h = og * tanh_fast(cn);
        const int row = lg * 4 + r;
        const int hid = w * 64 + c * 16 + lp;
        const int hbyte = (row * 512 + hid * 2) ^ ((row & 7) << 4);
        *(f16*)(smem + HB_OFF + hbyte) = (f16)h;
        p.out[((size_t)tt * 128 + bt * 16 + row) * 512 + (size_t)dir * 256 + hid] = h;
      }
    }

    // drain gx LDS-reads + h LDS-writes, then reissue DMA, then barrier2
    asm volatile("s_waitcnt lgkmcnt(0)" ::: "memory");
    __builtin_amdgcn_sched_barrier(0);
    {
      int ttn = tt + stp;
      ttn = ttn < 0 ? 0 : (ttn > SEQ - 1 ? SEQ - 1 : ttn);
      issue_gx(ttn * 8 + bt);
    }
    __builtin_amdgcn_s_barrier();
  }
}

// ---------------- launch -------------------------------------------------------
extern "C" void kernel_launch(void* const* d_in, const int* in_sizes, int n_in,
                              void* d_out, int out_size, void* d_ws, size_t ws_size,
                              hipStream_t stream) {
  (void)in_sizes; (void)n_in; (void)out_size;
  PrepP pp;
  const float* X = (const float*)d_in[0];
  for (int i = 0; i < 8; ++i) {
    pp.W[i]  = (const float*)d_in[1 + 2 * i];
    pp.Bv[i] = (const float*)d_in[2 + 2 * i];
  }
  char* ws = (char*)d_ws;
  pp.wx = (f16*)(ws + WX_OFF);
  pp.bias = (float*)(ws + BIAS_OFF);
  f16* gx = (f16*)(ws + GX_OFF);

  int nd;
  if (ws_size >= (size_t)GX_OFF + 2 * GXD) nd = 2;
  else if (ws_size >= (size_t)GX_OFF + GXD) nd = 1;
  else return;

  hipFuncSetAttribute(reinterpret_cast<const void*>(k_rec),
                      hipFuncAttributeMaxDynamicSharedMemorySize, REC_LDS);

  k_prep<<<dim3(512), dim3(256), 0, stream>>>(pp);

  const int passes = (nd == 2) ? 1 : 2;
  for (int ps = 0; ps < passes; ++ps) {
    const int d0 = (nd == 2) ? 0 : ps;
    GemP gp; gp.X = X; gp.wx = pp.wx; gp.bias = pp.bias; gp.gx = gx; gp.d0 = d0; gp.nd = nd;
    k_gemm<<<dim3(512 * 8 * nd), dim3(256), 0, stream>>>(gp);
    RecP rp;
    for (int i = 0; i < 8; ++i) rp.W[i] = pp.W[i];
    rp.gx = gx; rp.out = (float*)d_out; rp.d0 = d0;
    k_rec<<<dim3(8 * nd), dim3(256), REC_LDS, stream>>>(rp);
  }
}

// Round 4
// 2425.812 us; speedup vs baseline: 7.9502x; 1.3481x over previous
//
#include <hip/hip_runtime.h>
#include <stdint.h>

#define SEQ 512
#define BATCH 128
#define INDIM 256
#define HID 256
#define CS 512

typedef _Float16 f16;
typedef __attribute__((ext_vector_type(8))) _Float16 f16x8;
typedef __attribute__((ext_vector_type(4))) _Float16 f16x4;
typedef __attribute__((ext_vector_type(4))) float f32x4;

// ws layout:
//   [0,1MB)        wx   : [2][1024 n][256 k] f16
//   [1MB,1MB+8KB)  bias : [2048] f32
//   [4MB,...)      gx   : per dir 128MB: [mt 4096][w 4][g*2+cp 8][lane 64][16B]
#define WX_OFF   0u
#define BIAS_OFF (1u<<20)
#define GX_OFF   (4u<<20)
#define GXD ((size_t)4096 * 32768)   // 128MB per dir

__device__ __forceinline__ float sigm(float x) {
  return __builtin_amdgcn_rcpf(1.0f + __expf(-x));     // no f32 div
}
__device__ __forceinline__ float tanh_fast(float x) {
  return 1.0f - 2.0f * __builtin_amdgcn_rcpf(__expf(2.0f * x) + 1.0f);
}

__device__ __forceinline__ void load_lds16(const void* g, void* l) {
  __builtin_amdgcn_global_load_lds((const __attribute__((address_space(1))) void*)g,
                                   (__attribute__((address_space(3))) void*)l, 16, 0, 0);
}

// ---------------- kernel 1: Wx -> f16, bias table ------------------------------
struct PrepP { const float* W[8]; const float* Bv[8]; f16* wx; float* bias; };

__global__ __launch_bounds__(256) void k_prep(PrepP p) {
  const int u = blockIdx.x * 256 + threadIdx.x;       // 131072 threads exactly
  const int k4 = (u & 63) * 4;
  const int n = (u >> 6) & 1023;
  const int dir = u >> 16;
  const float* src = p.W[dir * 4 + (n >> 8)] + (size_t)(n & 255) * CS + HID + k4;
  f32x4 a = *(const f32x4*)src;
  f16x4 v;
  #pragma unroll
  for (int j = 0; j < 4; ++j) v[j] = (f16)a[j];
  *(f16x4*)(p.wx + ((size_t)dir * 1024 + n) * 256 + k4) = v;
  if (u < 2048) p.bias[u] = p.Bv[(u >> 10) * 4 + ((u >> 8) & 3)][u & 255];
}

// ---------------- kernel 2: Gx = X @ Wx^T + b  (f16, k_rec-DMA layout) ----------
struct GemP { const float* X; const f16* wx; const float* bias; f16* gx; int d0, nd; };

__global__ __launch_bounds__(256) void k_gemm(GemP p) {
  __shared__ float As[128 * 64];   // 32KB, rows 256B, XOR-swizzled
  __shared__ f16   Bs[128 * 64];   // 16KB, rows 128B, XOR-swizzled
  const int tid = threadIdx.x, l = tid & 63, w = tid >> 6;
  const int lp = l & 15, lg = l >> 4;
  const int NB = 8 * p.nd;
  const int nb = blockIdx.x % NB, mb = blockIdx.x / NB;
  const int m0 = mb * 128;
  const int wm = w >> 1, wn = w & 1;

  f32x4 acc[4][4];
  #pragma unroll
  for (int a = 0; a < 4; ++a)
    #pragma unroll
    for (int b = 0; b < 4; ++b) acc[a][b] = (f32x4){0.f, 0.f, 0.f, 0.f};

  auto stage = [&](int kb) {
    #pragma unroll
    for (int j = 0; j < 8; ++j) {
      const int i = w * 8 + j;
      const int rl = i * 4 + lg;
      const int kc = (lp * 16) ^ ((rl & 7) << 4);
      const char* g = (const char*)p.X + ((size_t)(m0 + rl) * 256 + (size_t)kb * 64) * 4 + kc;
      load_lds16(g, (char*)As + i * 1024 + l * 16);
    }
    #pragma unroll
    for (int j = 0; j < 4; ++j) {
      const int i = w * 4 + j;
      const int rl = i * 8 + (l >> 3);
      const int kc = ((l & 7) * 16) ^ ((rl & 7) << 4);
      const char* g = (const char*)p.wx + ((size_t)(p.d0 * 1024 + nb * 128 + rl) * 256 + (size_t)kb * 64) * 2 + kc;
      load_lds16(g, (char*)Bs + i * 1024 + l * 16);
    }
  };

  stage(0);
  for (int kb = 0; kb < 4; ++kb) {
    __syncthreads();
    #pragma unroll
    for (int ks = 0; ks < 2; ++ks) {
      f16x8 af[4];
      #pragma unroll
      for (int mi = 0; mi < 4; ++mi) {
        const int r = wm * 64 + mi * 16 + lp;
        const int kbyte = ks * 128 + lg * 32;
        const int sw = (r & 7) << 4;
        f32x4 a0 = *(const f32x4*)((const char*)As + r * 256 + (kbyte ^ sw));
        f32x4 a1 = *(const f32x4*)((const char*)As + r * 256 + ((kbyte + 16) ^ sw));
        f16x8 v;
        #pragma unroll
        for (int j = 0; j < 4; ++j) { v[j] = (f16)a0[j]; v[4 + j] = (f16)a1[j]; }
        af[mi] = v;
      }
      #pragma unroll
      for (int ni = 0; ni < 4; ++ni) {
        const int rn = wn * 64 + ni * 16 + lp;
        const int kbyte = (ks * 64 + lg * 16) ^ ((rn & 7) << 4);
        f16x8 bf = *(const f16x8*)((const char*)Bs + rn * 128 + kbyte);
        #pragma unroll
        for (int mi = 0; mi < 4; ++mi)
          acc[mi][ni] = __builtin_amdgcn_mfma_f32_16x16x32_f16(af[mi], bf, acc[mi][ni], 0, 0, 0);
      }
    }
    if (kb < 3) { __syncthreads(); stage(kb + 1); }
  }

  // epilogue: +bias, f16, store in k_rec DMA layout
  #pragma unroll
  for (int ni = 0; ni < 4; ++ni) {
    const int n_all = nb * 128 + wn * 64 + ni * 16 + lp;
    const float bv = p.bias[p.d0 * 1024 + n_all];
    const int gdl = n_all >> 10;
    const int n = n_all & 1023;
    const int g = n >> 8, hid = n & 255;
    const int wr = hid >> 6, c = (hid >> 4) & 3;
    #pragma unroll
    for (int mi = 0; mi < 4; ++mi) {
      const int mt = (m0 + wm * 64 + mi * 16) >> 4;
      f16x4 h4;
      #pragma unroll
      for (int r = 0; r < 4; ++r) h4[r] = (f16)(acc[mi][ni][r] + bv);
      char* dst = (char*)p.gx + (size_t)gdl * GXD
                + ((((size_t)mt * 4 + wr) * 8) + g * 2 + (c >> 1)) * 1024
                + (size_t)l * 16 + (c & 1) * 8;
      *(f16x4*)dst = h4;
    }
  }
}

// ---------------- kernel 3: block-local recurrence (no global sync) ------------
// LDS: [0,106496)        wt: wave w at w*26624, 13 (g,c) pairs x 2 k2 x 1KB
//      [106496,122880)   h: 2 buffers x (16 rows x 256 hid f16), byte ^= (row&7)<<4
//      [122880,155648)   gx: wave w at +w*8192, 8 chunks x 64 lanes x 16B
#define WTB_STRIDE 26624
#define HB_OFF  106496
#define GXB_OFF 122880
#define REC_LDS 155648

struct RecP { const float* W[8]; const f16* gx; float* out; int d0; };

__global__ __launch_bounds__(256, 1) void k_rec(RecP p) {
  extern __shared__ char smem[];
  const int tid = threadIdx.x, l = tid & 63, w = tid >> 6;
  const int lp = l & 15, lg = l >> 4;
  const int bx = blockIdx.x;
  const int dirl = bx >> 3;
  const int dir = p.d0 + dirl;
  const int bt = bx & 7;

  char* wtb = smem + w * WTB_STRIDE;
  char* gxb = smem + GXB_OFF + w * 8192;
  const char* gxd = (const char*)p.gx + (size_t)dirl * GXD;

  // ---- weights: f32 -> f16 fragments; ks<6 in regs; ks 6..7: lin 11,14,15 in
  //      regs (Brx), the other 13 (g,c) pairs in LDS ----
  f16x8 Br[4][4][6];
  f16x8 Brx[3][2];   // [0]=(g2,c3) lin11, [1]=(g3,c2) lin14, [2]=(g3,c3) lin15
  #pragma unroll
  for (int g = 0; g < 4; ++g) {
    #pragma unroll
    for (int c = 0; c < 4; ++c) {
      const float* wr = p.W[dir * 4 + g] + (size_t)(w * 64 + c * 16 + lp) * CS;
      #pragma unroll
      for (int ks = 0; ks < 8; ++ks) {
        f32x4 a0 = *(const f32x4*)(wr + ks * 32 + lg * 8);
        f32x4 a1 = *(const f32x4*)(wr + ks * 32 + lg * 8 + 4);
        f16x8 v;
        #pragma unroll
        for (int j = 0; j < 4; ++j) { v[j] = (f16)a0[j]; v[4 + j] = (f16)a1[j]; }
        const int lin = g * 4 + c;
        if (ks < 6) Br[g][c][ks] = v;
        else if (lin == 11) Brx[0][ks - 6] = v;
        else if (lin == 14) Brx[1][ks - 6] = v;
        else if (lin == 15) Brx[2][ks - 6] = v;
        else *(f16x8*)(wtb + ((lin - (lin >= 12 ? 1 : 0)) * 2 + (ks - 6)) * 1024 + (size_t)l * 16) = v;
      }
    }
  }

  float cst[4][4];
  #pragma unroll
  for (int c = 0; c < 4; ++c)
    #pragma unroll
    for (int r = 0; r < 4; ++r) cst[c][r] = 0.f;

  int tt = dir ? (SEQ - 1) : 0;
  const int stp = dir ? -1 : 1;

  // out addressing: uniform base + 32-bit per-thread offset
  float* outb = p.out + ((size_t)(bt * 16) * 512 + (size_t)dir * 256);
  const int vo = (lg * 4) * 512 + w * 64 + lp;     // dword offset at r=0,c=0

  auto issue_gx = [&](int mt) {
    const char* src = gxd + (((size_t)mt * 4 + w) * 8) * 1024 + (size_t)l * 16;
    #pragma unroll
    for (int ch = 0; ch < 8; ++ch)
      load_lds16(src + ch * 1024, gxb + ch * 1024 + (size_t)l * 16);
  };

  issue_gx(tt * 8 + bt);
  asm volatile("s_waitcnt vmcnt(0)" ::: "memory");
  __builtin_amdgcn_sched_barrier(0);
  __builtin_amdgcn_s_barrier();

  for (int t = 0; t < SEQ; ++t, tt += stp) {
    const int pr = ((t & 1) ^ 1) * 8192;   // read h buffer (valid for t>0)
    const int pw = (t & 1) * 8192;         // write h buffer

    f16x8 a[8];
    if (t > 0) {
      #pragma unroll
      for (int ks = 0; ks < 8; ++ks) {
        const int byte = ((lp * 512 + ks * 64 + lg * 16) ^ ((lp & 7) << 4)) + pr;
        a[ks] = *(const f16x8*)(smem + HB_OFF + byte);
      }
    }
    // gx DMA for this step landed; <=4 prior out-stores may still fly
    asm volatile("s_waitcnt vmcnt(4)" ::: "memory");
    __builtin_amdgcn_sched_barrier(0);

    float* outt = outb + (size_t)tt * (128 * 512);

    #pragma unroll
    for (int c = 0; c < 4; ++c) {
      f32x4 acc[4];
      #pragma unroll
      for (int g = 0; g < 4; ++g) {
        f16x4 gv = *(const f16x4*)(gxb + (g * 2 + (c >> 1)) * 1024 + (size_t)l * 16 + (c & 1) * 8);
        #pragma unroll
        for (int r = 0; r < 4; ++r) acc[g][r] = (float)gv[r];
      }
      if (c == 3) {
        // last gxb read done -> drain ds, issue next-step DMA (pinned in place)
        asm volatile("s_waitcnt lgkmcnt(0)" ::: "memory");
        __builtin_amdgcn_sched_barrier(0);
        int ttn = tt + stp;
        ttn = ttn < 0 ? 0 : (ttn > SEQ - 1 ? SEQ - 1 : ttn);
        issue_gx(ttn * 8 + bt);
        asm volatile("" ::: "memory");
        __builtin_amdgcn_sched_barrier(0);
      }
      if (t > 0) {
        #pragma unroll
        for (int ks = 0; ks < 6; ++ks)
          #pragma unroll
          for (int g = 0; g < 4; ++g)
            acc[g] = __builtin_amdgcn_mfma_f32_16x16x32_f16(a[ks], Br[g][c][ks], acc[g], 0, 0, 0);
        #pragma unroll
        for (int k2 = 0; k2 < 2; ++k2)
          #pragma unroll
          for (int g = 0; g < 4; ++g) {
            const int lin = g * 4 + c;
            f16x8 bv;
            if (lin == 11) bv = Brx[0][k2];
            else if (lin == 14) bv = Brx[1][k2];
            else if (lin == 15) bv = Brx[2][k2];
            else bv = *(const f16x8*)(wtb + ((lin - (lin >= 12 ? 1 : 0)) * 2 + k2) * 1024 + (size_t)l * 16);
            acc[g] = __builtin_amdgcn_mfma_f32_16x16x32_f16(a[6 + k2], bv, acc[g], 0, 0, 0);
          }
      }
      #pragma unroll
      for (int r = 0; r < 4; ++r) {
        const float fg = sigm(acc[0][r]);
        const float ig = sigm(acc[1][r]);
        const float cg = tanh_fast(acc[2][r]);
        const float og = sigm(acc[3][r]);
        const float cn = fg * cst[c][r] + ig * cg;
        cst[c][r] = cn;
        const float h = og * tanh_fast(cn);
        const int row = lg * 4 + r;
        const int hid = w * 64 + c * 16 + lp;
        const int hbyte = ((row * 512 + hid * 2) ^ ((row & 7) << 4)) + pw;
        *(f16*)(smem + HB_OFF + hbyte) = (f16)h;
        outt[vo + r * 512 + c * 16] = h;
      }
    }

    // h writes visible to all waves before next step's h reads
    asm volatile("s_waitcnt lgkmcnt(0)" ::: "memory");
    __builtin_amdgcn_sched_barrier(0);
    __builtin_amdgcn_s_barrier();
  }
}

// ---------------- launch -------------------------------------------------------
extern "C" void kernel_launch(void* const* d_in, const int* in_sizes, int n_in,
                              void* d_out, int out_size, void* d_ws, size_t ws_size,
                              hipStream_t stream) {
  (void)in_sizes; (void)n_in; (void)out_size;
  PrepP pp;
  const float* X = (const float*)d_in[0];
  for (int i = 0; i < 8; ++i) {
    pp.W[i]  = (const float*)d_in[1 + 2 * i];
    pp.Bv[i] = (const float*)d_in[2 + 2 * i];
  }
  char* ws = (char*)d_ws;
  pp.wx = (f16*)(ws + WX_OFF);
  pp.bias = (float*)(ws + BIAS_OFF);
  f16* gx = (f16*)(ws + GX_OFF);

  int nd;
  if (ws_size >= (size_t)GX_OFF + 2 * GXD) nd = 2;
  else if (ws_size >= (size_t)GX_OFF + GXD) nd = 1;
  else return;

  hipFuncSetAttribute(reinterpret_cast<const void*>(k_rec),
                      hipFuncAttributeMaxDynamicSharedMemorySize, REC_LDS);

  k_prep<<<dim3(512), dim3(256), 0, stream>>>(pp);

  const int passes = (nd == 2) ? 1 : 2;
  for (int ps = 0; ps < passes; ++ps) {
    const int d0 = (nd == 2) ? 0 : ps;
    GemP gp; gp.X = X; gp.wx = pp.wx; gp.bias = pp.bias; gp.gx = gx; gp.d0 = d0; gp.nd = nd;
    k_gemm<<<dim3(512 * 8 * nd), dim3(256), 0, stream>>>(gp);
    RecP rp;
    for (int i = 0; i < 8; ++i) rp.W[i] = pp.W[i];
    rp.gx = gx; rp.out = (float*)d_out; rp.d0 = d0;
    k_rec<<<dim3(8 * nd), dim3(256), REC_LDS, stream>>>(rp);
  }
}